// Round 1
// baseline (1330.374 us; speedup 1.0000x reference)
//
#include <hip/hip_runtime.h>
#include <hip/hip_bf16.h>
#include <stdint.h>

#define S_LEN 2048
#define HID   4096
#define NH    32
#define NKV   8
#define HD    128
#define SCALE 0.08838834764831845f

using bf16   = __hip_bfloat16;
using bf16x8 = __attribute__((ext_vector_type(8))) __bf16;
using f32x4  = __attribute__((ext_vector_type(4))) float;

__device__ __forceinline__ void gl2lds(const void* g, void* l) {
  __builtin_amdgcn_global_load_lds(
      (const __attribute__((address_space(1))) unsigned int*)(uintptr_t)g,
      (__attribute__((address_space(3))) unsigned int*)(uintptr_t)l, 16, 0, 0);
}

__device__ __forceinline__ f32x4 mfma16(bf16x8 a, bf16x8 b, f32x4 c) {
  return __builtin_amdgcn_mfma_f32_16x16x32_bf16(a, b, c, 0, 0, 0);
}

// ---------------- cast f32 -> bf16 (flat) ----------------
__global__ void cast_f32_bf16(const float* __restrict__ in, bf16* __restrict__ out) {
  size_t i = ((size_t)blockIdx.x * 256 + threadIdx.x) * 4;
  float4 v = *(const float4*)(in + i);
  __hip_bfloat162 a, b;
  a.x = __float2bfloat16(v.x); a.y = __float2bfloat16(v.y);
  b.x = __float2bfloat16(v.z); b.y = __float2bfloat16(v.w);
  *(__hip_bfloat162*)(out + i)     = a;
  *(__hip_bfloat162*)(out + i + 2) = b;
}

// ---------------- transpose+cast: in f32 [K][N] -> out bf16 [N][K] ----------------
__global__ void transpose_cast(const float* __restrict__ in, bf16* __restrict__ out,
                               int K, int N) {
  __shared__ float tile[64][65];
  int n0 = blockIdx.x * 64, k0 = blockIdx.y * 64;
  for (int i = 0; i < 16; i++) {
    int lin = i * 256 + threadIdx.x;
    int r = lin >> 6, c = lin & 63;
    tile[r][c] = in[(size_t)(k0 + r) * N + n0 + c];
  }
  __syncthreads();
  for (int i = 0; i < 16; i++) {
    int lin = i * 256 + threadIdx.x;
    int r = lin >> 6, c = lin & 63;
    out[(size_t)(n0 + r) * K + k0 + c] = __float2bfloat16(tile[c][r]);
  }
}

// ---------------- bf16 GEMM, B^T input (m97 structure) ----------------
// C[M][N] = A[M][K] * Bt[N][K]^T.  EPI 0: C f32 row-major.
// EPI 1 (V proj): C = new_v f32 [8][S][128]; Caux = v^T bf16 [8][128][S].
template <int EPI>
__global__ __launch_bounds__(256) void gemm_bt(const bf16* __restrict__ A,
                                               const bf16* __restrict__ Bt,
                                               float* __restrict__ C,
                                               bf16* __restrict__ Caux,
                                               int M, int N, int K) {
  __shared__ bf16 Asm[128 * 32];
  __shared__ bf16 Bsm[128 * 32];
  const int tid = threadIdx.x;
  const int lane = tid & 63, wv = tid >> 6;
  const int quad = lane >> 4, l16 = lane & 15;
  const int wm = wv >> 1, wn = wv & 1;
  const size_t bm = (size_t)blockIdx.y * 128, bn = (size_t)blockIdx.x * 128;
  const bf16* Ab = A + bm * K;
  const bf16* Bb = Bt + bn * K;
  f32x4 acc[4][4];
  for (int i = 0; i < 4; i++)
    for (int j = 0; j < 4; j++) acc[i][j] = 0.f;
  const int c0 = tid, c1 = 256 + tid;
  const int r0 = c0 >> 2, kc0 = (c0 & 3) << 3;
  const int r1 = c1 >> 2, kc1 = (c1 & 3) << 3;
  for (int k0 = 0; k0 < K; k0 += 32) {
    gl2lds(Ab + (size_t)r0 * K + k0 + kc0, (char*)Asm + c0 * 16);
    gl2lds(Ab + (size_t)r1 * K + k0 + kc1, (char*)Asm + c1 * 16);
    gl2lds(Bb + (size_t)r0 * K + k0 + kc0, (char*)Bsm + c0 * 16);
    gl2lds(Bb + (size_t)r1 * K + k0 + kc1, (char*)Bsm + c1 * 16);
    __syncthreads();
    bf16x8 af[4], bfr[4];
    for (int t = 0; t < 4; t++) {
      af[t]  = *(const bf16x8*)(Asm + (wm * 64 + t * 16 + l16) * 32 + quad * 8);
      bfr[t] = *(const bf16x8*)(Bsm + (wn * 64 + t * 16 + l16) * 32 + quad * 8);
    }
    for (int mt = 0; mt < 4; mt++)
      for (int nt = 0; nt < 4; nt++)
        acc[mt][nt] = mfma16(af[mt], bfr[nt], acc[mt][nt]);
    __syncthreads();
  }
  for (int mt = 0; mt < 4; mt++)
    for (int nt = 0; nt < 4; nt++)
      for (int r = 0; r < 4; r++) {
        size_t mm = bm + wm * 64 + mt * 16 + quad * 4 + r;
        size_t nn = bn + wn * 64 + nt * 16 + l16;
        float v = acc[mt][nt][r];
        if constexpr (EPI == 0) {
          C[mm * N + nn] = v;
        } else {
          int hh = (int)(nn >> 7), dd = (int)(nn & 127);
          C[((size_t)hh * S_LEN + mm) * HD + dd] = v;
          Caux[((size_t)hh * HD + dd) * S_LEN + mm] = __float2bfloat16(v);
        }
      }
}

// ---------------- per-head RMSNorm + RoPE ----------------
// xin: [S][nh*128] f32 (row = t*nh+h).  Writes xbf [nh][S][128] bf16 and
// optionally fout [nh][S][128] f32 (new_k).
__global__ __launch_bounds__(256) void norm_rope(const float* __restrict__ xin,
                                                 const float* __restrict__ w,
                                                 const int* __restrict__ pos,
                                                 bf16* __restrict__ xbf,
                                                 float* __restrict__ fout, int nh) {
  const int wv = threadIdx.x >> 6, lane = threadIdx.x & 63;
  const int row = blockIdx.x * 4 + wv;
  const int t = row / nh, h = row - t * nh;
  float2 x = *(const float2*)(xin + (size_t)row * 128 + lane * 2);
  float ss = x.x * x.x + x.y * x.y;
  for (int off = 32; off >= 1; off >>= 1) ss += __shfl_xor(ss, off, 64);
  float rr = rsqrtf(ss * (1.f / 128.f) + 1e-6f);
  float2 wv2 = *(const float2*)(w + lane * 2);
  float xn0 = x.x * rr * wv2.x, xn1 = x.y * rr * wv2.y;
  float p = (float)pos[t];
  int i0 = (lane & 31) * 2;
  const float k = 13.815510557964274f / 64.f;  // ln(1e6)/64
  float f0 = p * expf(-(float)i0 * k);
  float f1 = p * expf(-(float)(i0 + 1) * k);
  float c0 = cosf(f0), s0 = sinf(f0), c1 = cosf(f1), s1 = sinf(f1);
  float y0 = __shfl_xor(xn0, 32, 64), y1 = __shfl_xor(xn1, 32, 64);
  float o0, o1;
  if (lane < 32) { o0 = xn0 * c0 - y0 * s0; o1 = xn1 * c1 - y1 * s1; }
  else           { o0 = xn0 * c0 + y0 * s0; o1 = xn1 * c1 + y1 * s1; }
  size_t ob = ((size_t)h * S_LEN + t) * 128 + lane * 2;
  __hip_bfloat162 bb;
  bb.x = __float2bfloat16(o0); bb.y = __float2bfloat16(o1);
  *(__hip_bfloat162*)(xbf + ob) = bb;
  if (fout) { float2 f2; f2.x = o0; f2.y = o1; *(float2*)(fout + ob) = f2; }
}

// ---------------- attention: scores + softmax + probs + PV ----------------
// qb [32][S][128] bf16, kb [8][S][128] bf16, vt [8][128][S] bf16.
// probs [32][S][S] f32 out; attnb [S][4096] bf16 out.
// Block = (head, 64-row q-tile); 4 waves, 16 rows each.
__global__ __launch_bounds__(256) void attn_kernel(const bf16* __restrict__ qb,
                                                   const bf16* __restrict__ kb,
                                                   const bf16* __restrict__ vt,
                                                   float* __restrict__ probs,
                                                   bf16* __restrict__ attnb) {
  __shared__ bf16 Ksm[64 * 128];   // [k-token][d], 16B slots xor-swizzled
  __shared__ bf16 Vsm[128 * 64];   // [d][k-token], 16B slots xor-swizzled
  __shared__ bf16 Psm[4 * 16 * 72];  // per-wave P tile, row stride 72
  const int h = blockIdx.y, bq = blockIdx.x;
  const int hk = h >> 2;
  const int tid = threadIdx.x;
  const int lane = tid & 63, wv = tid >> 6;
  const int quad = lane >> 4, l16 = lane & 15;
  const int q0 = bq * 64, rbase = q0 + wv * 16;

  bf16x8 qf[4];
  {
    const bf16* qp = qb + ((size_t)h * S_LEN + rbase + l16) * HD + quad * 8;
    for (int ks = 0; ks < 4; ks++) qf[ks] = *(const bf16x8*)(qp + ks * 32);
  }
  const bf16* kbase = kb + (size_t)hk * S_LEN * HD;
  const bf16* vbase = vt + (size_t)hk * HD * S_LEN;

  float m[4], l[4];
  for (int r = 0; r < 4; r++) { m[r] = -1e30f; l[r] = 0.f; }

  // ---- pass 1: softmax stats ----
  for (int kt = 0; kt <= bq; kt++) {
    for (int i = 0; i < 4; i++) {
      int c = i * 256 + tid;
      int krow = c >> 4, j = c & 15;
      gl2lds(kbase + (size_t)kt * 8192 + (size_t)krow * 128 + ((j ^ (krow & 7)) << 3),
             (char*)Ksm + c * 16);
    }
    __syncthreads();
    f32x4 s[4];
    for (int nt = 0; nt < 4; nt++) s[nt] = 0.f;
    for (int ks = 0; ks < 4; ks++)
      for (int nt = 0; nt < 4; nt++) {
        int krow = nt * 16 + l16;
        int slot = (ks * 4 + quad) ^ (krow & 7);
        bf16x8 kf = *(const bf16x8*)(Ksm + krow * 128 + slot * 8);
        s[nt] = mfma16(qf[ks], kf, s[nt]);
      }
    for (int r = 0; r < 4; r++) {
      const int rowg = rbase + quad * 4 + r;
      float vv[4], tm = -1e30f;
      for (int nt = 0; nt < 4; nt++) {
        int col = kt * 64 + nt * 16 + l16;
        float v = s[nt][r] * SCALE;
        v = (col <= rowg) ? v : -1e30f;
        vv[nt] = v;
        tm = fmaxf(tm, v);
      }
      for (int off = 1; off < 16; off <<= 1) tm = fmaxf(tm, __shfl_xor(tm, off, 64));
      float nm = fmaxf(m[r], tm);
      float se = 0.f;
      for (int nt = 0; nt < 4; nt++) se += __expf(vv[nt] - nm);
      for (int off = 1; off < 16; off <<= 1) se += __shfl_xor(se, off, 64);
      l[r] = l[r] * __expf(m[r] - nm) + se;
      m[r] = nm;
    }
    __syncthreads();
  }

  float invl[4];
  for (int r = 0; r < 4; r++) invl[r] = 1.f / l[r];
  f32x4 o[8];
  for (int n2 = 0; n2 < 8; n2++) o[n2] = 0.f;

  // ---- pass 2: probs write + PV ----
  for (int kt = 0; kt < 32; kt++) {
    if (kt > bq) {  // fully-masked tile: write zeros (block-uniform branch)
      for (int r = 0; r < 4; r++) {
        float* pp = probs + ((size_t)h * S_LEN + rbase + quad * 4 + r) * S_LEN + kt * 64 + l16;
        for (int nt = 0; nt < 4; nt++) pp[nt * 16] = 0.f;
      }
      continue;
    }
    for (int i = 0; i < 4; i++) {
      int c = i * 256 + tid;
      int krow = c >> 4, j = c & 15;
      gl2lds(kbase + (size_t)kt * 8192 + (size_t)krow * 128 + ((j ^ (krow & 7)) << 3),
             (char*)Ksm + c * 16);
      int d = c >> 3, jv = c & 7;
      gl2lds(vbase + (size_t)d * S_LEN + kt * 64 + ((jv ^ (d & 7)) << 3),
             (char*)Vsm + c * 16);
    }
    __syncthreads();
    f32x4 s[4];
    for (int nt = 0; nt < 4; nt++) s[nt] = 0.f;
    for (int ks = 0; ks < 4; ks++)
      for (int nt = 0; nt < 4; nt++) {
        int krow = nt * 16 + l16;
        int slot = (ks * 4 + quad) ^ (krow & 7);
        bf16x8 kf = *(const bf16x8*)(Ksm + krow * 128 + slot * 8);
        s[nt] = mfma16(qf[ks], kf, s[nt]);
      }
    for (int r = 0; r < 4; r++) {
      const int rowg = rbase + quad * 4 + r;
      float* pp = probs + ((size_t)h * S_LEN + rowg) * S_LEN + kt * 64;
      for (int nt = 0; nt < 4; nt++) {
        int col = kt * 64 + nt * 16 + l16;
        float p = (col <= rowg) ? __expf(s[nt][r] * SCALE - m[r]) * invl[r] : 0.f;
        pp[nt * 16 + l16] = p;
        Psm[wv * 1152 + (quad * 4 + r) * 72 + nt * 16 + l16] = __float2bfloat16(p);
      }
    }
    asm volatile("s_waitcnt lgkmcnt(0)" ::: "memory");  // P write -> P read (same wave)
    bf16x8 pf0 = *(const bf16x8*)(Psm + wv * 1152 + l16 * 72 + quad * 8);
    bf16x8 pf1 = *(const bf16x8*)(Psm + wv * 1152 + l16 * 72 + 32 + quad * 8);
    for (int n2 = 0; n2 < 8; n2++) {
      int vrow = n2 * 16 + l16;
      int s0 = quad ^ (vrow & 7), s1 = (4 + quad) ^ (vrow & 7);
      bf16x8 vb0 = *(const bf16x8*)(Vsm + vrow * 64 + s0 * 8);
      bf16x8 vb1 = *(const bf16x8*)(Vsm + vrow * 64 + s1 * 8);
      o[n2] = mfma16(pf0, vb0, o[n2]);
      o[n2] = mfma16(pf1, vb1, o[n2]);
    }
    __syncthreads();
  }
  for (int n2 = 0; n2 < 8; n2++)
    for (int r = 0; r < 4; r++)
      attnb[((size_t)(rbase + quad * 4 + r)) * HID + h * HD + n2 * 16 + l16] =
          __float2bfloat16(o[n2][r]);
}

extern "C" void kernel_launch(void* const* d_in, const int* in_sizes, int n_in,
                              void* d_out, int out_size, void* d_ws, size_t ws_size,
                              hipStream_t stream) {
  const float* hidden = (const float*)d_in[0];
  const int*   pos    = (const int*)d_in[1];
  const float* Wq     = (const float*)d_in[2];
  const float* Wk     = (const float*)d_in[3];
  const float* Wv     = (const float*)d_in[4];
  const float* Wo     = (const float*)d_in[5];
  const float* qw     = (const float*)d_in[6];
  const float* kw     = (const float*)d_in[7];

  float* out   = (float*)d_out;
  float* newk  = out + (size_t)S_LEN * HID;
  float* newv  = newk + (size_t)NKV * S_LEN * HD;
  float* probs = newv + (size_t)NKV * S_LEN * HD;

  char* w = (char*)d_ws;
  bf16* hb   = (bf16*)w;  w += (size_t)S_LEN * HID * 2;   // 16M; reused as qbf
  bf16* wqt  = (bf16*)w;  w += (size_t)HID * HID * 2;     // 32M; reused as wot
  bf16* wkt  = (bf16*)w;  w += (size_t)1024 * HID * 2;    // 8M;  reused as kbf
  bf16* wvt  = (bf16*)w;  w += (size_t)1024 * HID * 2;    // 8M
  float* qraw = (float*)w; w += (size_t)S_LEN * HID * 4;  // 32M; reused as attnb
  float* kraw = (float*)w; w += (size_t)S_LEN * 1024 * 4; // 8M
  bf16* vtb  = (bf16*)w;  w += (size_t)NKV * HD * S_LEN * 2;  // 4M
  bf16* qbf   = hb;
  bf16* wot   = wqt;
  bf16* kbf   = wkt;
  bf16* attnb = (bf16*)qraw;

  cast_f32_bf16<<<(S_LEN * HID) / 1024, 256, 0, stream>>>(hidden, hb);
  transpose_cast<<<dim3(HID / 64, HID / 64), 256, 0, stream>>>(Wq, wqt, HID, HID);
  transpose_cast<<<dim3(1024 / 64, HID / 64), 256, 0, stream>>>(Wk, wkt, HID, 1024);
  transpose_cast<<<dim3(1024 / 64, HID / 64), 256, 0, stream>>>(Wv, wvt, HID, 1024);

  gemm_bt<0><<<dim3(HID / 128, S_LEN / 128), 256, 0, stream>>>(hb, wqt, qraw, nullptr, S_LEN, HID, HID);
  gemm_bt<0><<<dim3(1024 / 128, S_LEN / 128), 256, 0, stream>>>(hb, wkt, kraw, nullptr, S_LEN, 1024, HID);
  gemm_bt<1><<<dim3(1024 / 128, S_LEN / 128), 256, 0, stream>>>(hb, wvt, newv, vtb, S_LEN, 1024, HID);

  norm_rope<<<(S_LEN * NKV) / 4, 256, 0, stream>>>(kraw, kw, pos, kbf, newk, NKV);
  norm_rope<<<(S_LEN * NH) / 4, 256, 0, stream>>>(qraw, qw, pos, qbf, nullptr, NH);
  transpose_cast<<<dim3(HID / 64, HID / 64), 256, 0, stream>>>(Wo, wot, HID, HID);

  attn_kernel<<<dim3(32, 32), 256, 0, stream>>>(qbf, kbf, vtb, probs, attnb);
  gemm_bt<0><<<dim3(HID / 128, S_LEN / 128), 256, 0, stream>>>(attnb, wot, out, nullptr, S_LEN, HID, HID);
}

// Round 2
// 1178.613 us; speedup vs baseline: 1.1288x; 1.1288x over previous
//
#include <hip/hip_runtime.h>
#include <hip/hip_bf16.h>
#include <stdint.h>

#define S_LEN 2048
#define HID   4096
#define NH    32
#define NKV   8
#define HD    128
#define SCALE 0.08838834764831845f

using bf16   = __hip_bfloat16;
using bf16x8 = __attribute__((ext_vector_type(8))) __bf16;
using f32x4  = __attribute__((ext_vector_type(4))) float;

__device__ __forceinline__ void gl2lds(const void* g, void* l) {
  __builtin_amdgcn_global_load_lds(
      (const __attribute__((address_space(1))) unsigned int*)(uintptr_t)g,
      (__attribute__((address_space(3))) unsigned int*)(uintptr_t)l, 16, 0, 0);
}

__device__ __forceinline__ f32x4 mfma16(bf16x8 a, bf16x8 b, f32x4 c) {
  return __builtin_amdgcn_mfma_f32_16x16x32_bf16(a, b, c, 0, 0, 0);
}

// ---------------- cast f32 -> bf16 (flat) ----------------
__global__ void cast_f32_bf16(const float* __restrict__ in, bf16* __restrict__ out) {
  size_t i = ((size_t)blockIdx.x * 256 + threadIdx.x) * 4;
  float4 v = *(const float4*)(in + i);
  __hip_bfloat162 a, b;
  a.x = __float2bfloat16(v.x); a.y = __float2bfloat16(v.y);
  b.x = __float2bfloat16(v.z); b.y = __float2bfloat16(v.w);
  *(__hip_bfloat162*)(out + i)     = a;
  *(__hip_bfloat162*)(out + i + 2) = b;
}

// ---------------- transpose+cast: in f32 [K][N] -> out bf16 [N][K] ----------------
__global__ __launch_bounds__(256) void transpose_cast(const float* __restrict__ in,
                                                      bf16* __restrict__ out,
                                                      int K, int N) {
  __shared__ float tile[64][69];
  const int n0 = blockIdx.x * 64, k0 = blockIdx.y * 64;
  const int rr = threadIdx.x >> 4, cc = (threadIdx.x & 15) * 4;
  for (int i = 0; i < 4; i++) {
    int r = i * 16 + rr;
    float4 v = *(const float4*)(in + (size_t)(k0 + r) * N + n0 + cc);
    tile[r][cc] = v.x; tile[r][cc + 1] = v.y; tile[r][cc + 2] = v.z; tile[r][cc + 3] = v.w;
  }
  __syncthreads();
  for (int i = 0; i < 4; i++) {
    int n = i * 16 + rr;
    union { unsigned long long u8; unsigned short us[4]; } pk;
    for (int j = 0; j < 4; j++) {
      bf16 b = __float2bfloat16(tile[cc + j][n]);
      pk.us[j] = *(unsigned short*)&b;
    }
    *(unsigned long long*)(out + (size_t)(n0 + n) * K + k0 + cc) = pk.u8;
  }
}

// ---------------- bf16 GEMM, B^T input (m97 structure) ----------------
// EPI 0: C f32 row-major [M][N].
// EPI 2: combined QKV. nn<4096 -> C(qraw [M][4096]); nn<5120 -> C2(kraw [M][1024]);
//        else C3 = new_v f32 [8][S][128] and Caux = v^T bf16 [8][128][S] token-PERMUTED
//        (within each 32-token group: pos = (t&15>>2)*8 + (t&3) + ((t&16)>>2)).
template <int EPI>
__global__ __launch_bounds__(256) void gemm_bt(const bf16* __restrict__ A,
                                               const bf16* __restrict__ Bt,
                                               float* __restrict__ C,
                                               float* __restrict__ C2,
                                               float* __restrict__ C3,
                                               bf16* __restrict__ Caux,
                                               int M, int N, int K) {
  __shared__ bf16 Asm[128 * 32];
  __shared__ bf16 Bsm[128 * 32];
  const int tid = threadIdx.x;
  const int lane = tid & 63, wv = tid >> 6;
  const int quad = lane >> 4, l16 = lane & 15;
  const int wm = wv >> 1, wn = wv & 1;
  const size_t bm = (size_t)blockIdx.y * 128, bn = (size_t)blockIdx.x * 128;
  const bf16* Ab = A + bm * K;
  const bf16* Bb = Bt + bn * K;
  f32x4 acc[4][4];
  for (int i = 0; i < 4; i++)
    for (int j = 0; j < 4; j++) acc[i][j] = 0.f;
  const int c0 = tid, c1 = 256 + tid;
  const int r0 = c0 >> 2, kc0 = (c0 & 3) << 3;
  const int r1 = c1 >> 2, kc1 = (c1 & 3) << 3;
  for (int k0 = 0; k0 < K; k0 += 32) {
    gl2lds(Ab + (size_t)r0 * K + k0 + kc0, (char*)Asm + c0 * 16);
    gl2lds(Ab + (size_t)r1 * K + k0 + kc1, (char*)Asm + c1 * 16);
    gl2lds(Bb + (size_t)r0 * K + k0 + kc0, (char*)Bsm + c0 * 16);
    gl2lds(Bb + (size_t)r1 * K + k0 + kc1, (char*)Bsm + c1 * 16);
    __syncthreads();
    bf16x8 af[4], bfr[4];
    for (int t = 0; t < 4; t++) {
      af[t]  = *(const bf16x8*)(Asm + (wm * 64 + t * 16 + l16) * 32 + quad * 8);
      bfr[t] = *(const bf16x8*)(Bsm + (wn * 64 + t * 16 + l16) * 32 + quad * 8);
    }
    for (int mt = 0; mt < 4; mt++)
      for (int nt = 0; nt < 4; nt++)
        acc[mt][nt] = mfma16(af[mt], bfr[nt], acc[mt][nt]);
    __syncthreads();
  }
  for (int mt = 0; mt < 4; mt++)
    for (int nt = 0; nt < 4; nt++)
      for (int r = 0; r < 4; r++) {
        size_t mm = bm + wm * 64 + mt * 16 + quad * 4 + r;
        size_t nn = bn + wn * 64 + nt * 16 + l16;
        float v = acc[mt][nt][r];
        if constexpr (EPI == 0) {
          C[mm * N + nn] = v;
        } else {
          if (bn < 4096) {
            C[mm * 4096 + nn] = v;
          } else if (bn < 5120) {
            C2[mm * 1024 + (nn - 4096)] = v;
          } else {
            int nl = (int)(nn - 5120);
            int hh = nl >> 7, dd = nl & 127;
            C3[((size_t)hh * S_LEN + mm) * HD + dd] = v;
            int t = (int)mm;
            int tp = (t & ~31) + (((t & 15) >> 2) * 8) + (t & 3) + ((t & 16) >> 2);
            Caux[((size_t)hh * HD + dd) * S_LEN + tp] = __float2bfloat16(v);
          }
        }
      }
}

// ---------------- per-head RMSNorm + RoPE ----------------
__global__ __launch_bounds__(256) void norm_rope(const float* __restrict__ xin,
                                                 const float* __restrict__ w,
                                                 const int* __restrict__ pos,
                                                 bf16* __restrict__ xbf,
                                                 float* __restrict__ fout, int nh) {
  const int wv = threadIdx.x >> 6, lane = threadIdx.x & 63;
  const int row = blockIdx.x * 4 + wv;
  const int t = row / nh, h = row - t * nh;
  float2 x = *(const float2*)(xin + (size_t)row * 128 + lane * 2);
  float ss = x.x * x.x + x.y * x.y;
  for (int off = 32; off >= 1; off >>= 1) ss += __shfl_xor(ss, off, 64);
  float rr = rsqrtf(ss * (1.f / 128.f) + 1e-6f);
  float2 wv2 = *(const float2*)(w + lane * 2);
  float xn0 = x.x * rr * wv2.x, xn1 = x.y * rr * wv2.y;
  float p = (float)pos[t];
  int i0 = (lane & 31) * 2;
  const float k = 13.815510557964274f / 64.f;  // ln(1e6)/64
  float f0 = p * expf(-(float)i0 * k);
  float f1 = p * expf(-(float)(i0 + 1) * k);
  float c0 = cosf(f0), s0 = sinf(f0), c1 = cosf(f1), s1 = sinf(f1);
  float y0 = __shfl_xor(xn0, 32, 64), y1 = __shfl_xor(xn1, 32, 64);
  float o0, o1;
  if (lane < 32) { o0 = xn0 * c0 - y0 * s0; o1 = xn1 * c1 - y1 * s1; }
  else           { o0 = xn0 * c0 + y0 * s0; o1 = xn1 * c1 + y1 * s1; }
  size_t ob = ((size_t)h * S_LEN + t) * 128 + lane * 2;
  __hip_bfloat162 bb;
  bb.x = __float2bfloat16(o0); bb.y = __float2bfloat16(o1);
  *(__hip_bfloat162*)(xbf + ob) = bb;
  if (fout) { float2 f2; f2.x = o0; f2.y = o1; *(float2*)(fout + ob) = f2; }
}

// ---------------- attention ----------------
// qb [32][S][128] bf16, kb [8][S][128] bf16, vt [8][128][S] bf16 (token-permuted).
// probs [32][S][S] f32; attnb [S][4096] bf16.
// Scores computed TRANSPOSED (mfma(Kfrag,Qfrag)) so each lane holds row=l16,
// tokens=quad*4+r -> P stays in registers as the PV B-fragment (no LDS round-trip),
// probs written as float4. Softmax uses m=0 (RMSNorm bounds |s*scale|<=11.32).
__global__ __launch_bounds__(256) void attn_kernel(const bf16* __restrict__ qb,
                                                   const bf16* __restrict__ kb,
                                                   const bf16* __restrict__ vt,
                                                   float* __restrict__ probs,
                                                   bf16* __restrict__ attnb) {
  __shared__ bf16 Ksm[64 * 128];   // [tok][d], 16B slots xor-swizzled
  __shared__ bf16 Vsm[128 * 64];   // [d][tok(perm)], 16B slots xor-swizzled
  const int h = blockIdx.y, bq = 31 - blockIdx.x;  // heavy tiles first
  const int hk = h >> 2;
  const int tid = threadIdx.x;
  const int lane = tid & 63, wv = tid >> 6;
  const int quad = lane >> 4, l16 = lane & 15;
  const int g = bq * 64 + wv * 16 + l16;  // this lane's q-row

  bf16x8 qf[4];
  {
    const bf16* qp = qb + ((size_t)h * S_LEN + g) * HD + quad * 8;
    for (int ks = 0; ks < 4; ks++) qf[ks] = *(const bf16x8*)(qp + ks * 32);
  }
  const bf16* kbase = kb + (size_t)hk * S_LEN * HD;
  const bf16* vbase = vt + (size_t)hk * HD * S_LEN;

  float L = 0.f;
  // ---- pass 1: row sums of exp(s) (no max needed; no shuffles in loop) ----
  for (int kt = 0; kt <= bq; kt++) {
    for (int i = 0; i < 4; i++) {
      int c = i * 256 + tid;
      int krow = c >> 4, j = c & 15;
      gl2lds(kbase + (size_t)kt * 8192 + (size_t)krow * 128 + ((j ^ (krow & 7)) << 3),
             (char*)Ksm + c * 16);
    }
    __syncthreads();
    f32x4 s[4];
    for (int mt = 0; mt < 4; mt++) s[mt] = 0.f;
    for (int ks = 0; ks < 4; ks++)
      for (int mt = 0; mt < 4; mt++) {
        int tok = mt * 16 + l16;
        int slot = (ks * 4 + quad) ^ (tok & 7);
        bf16x8 kf = *(const bf16x8*)(Ksm + tok * 128 + slot * 8);
        s[mt] = mfma16(kf, qf[ks], s[mt]);  // S^T: lane row=l16, tok=quad*4+r
      }
    for (int mt = 0; mt < 4; mt++)
      for (int r = 0; r < 4; r++) {
        int tk = kt * 64 + mt * 16 + quad * 4 + r;
        if (tk <= g) L += __expf(s[mt][r] * SCALE);
      }
    __syncthreads();
  }
  L += __shfl_xor(L, 16, 64);
  L += __shfl_xor(L, 32, 64);
  const float invl = 1.f / L;

  f32x4 o[8];
  for (int dt = 0; dt < 8; dt++) o[dt] = 0.f;

  // ---- pass 2: probs write (float4) + PV (P in registers) ----
  for (int kt = 0; kt < 32; kt++) {
    float* pbase = probs + ((size_t)h * S_LEN + g) * S_LEN + kt * 64;
    if (kt > bq) {  // fully-masked tile: zero-fill
      f32x4 z = 0.f;
      for (int mt = 0; mt < 4; mt++) *(f32x4*)(pbase + mt * 16 + quad * 4) = z;
      continue;
    }
    for (int i = 0; i < 4; i++) {
      int c = i * 256 + tid;
      int krow = c >> 4, j = c & 15;
      gl2lds(kbase + (size_t)kt * 8192 + (size_t)krow * 128 + ((j ^ (krow & 7)) << 3),
             (char*)Ksm + c * 16);
      int d = c >> 3, jv = c & 7;
      gl2lds(vbase + (size_t)d * S_LEN + kt * 64 + ((jv ^ (d & 7)) << 3),
             (char*)Vsm + c * 16);
    }
    __syncthreads();
    f32x4 s[4];
    for (int mt = 0; mt < 4; mt++) s[mt] = 0.f;
    for (int ks = 0; ks < 4; ks++)
      for (int mt = 0; mt < 4; mt++) {
        int tok = mt * 16 + l16;
        int slot = (ks * 4 + quad) ^ (tok & 7);
        bf16x8 kf = *(const bf16x8*)(Ksm + tok * 128 + slot * 8);
        s[mt] = mfma16(kf, qf[ks], s[mt]);
      }
    f32x4 p[4];
    for (int mt = 0; mt < 4; mt++) {
      for (int r = 0; r < 4; r++) {
        int tk = kt * 64 + mt * 16 + quad * 4 + r;
        p[mt][r] = (tk <= g) ? __expf(s[mt][r] * SCALE) * invl : 0.f;
      }
      *(f32x4*)(pbase + mt * 16 + quad * 4) = p[mt];
    }
    for (int kstep = 0; kstep < 2; kstep++) {
      union { bf16x8 v; bf16 hh[8]; } pb;
      for (int j = 0; j < 4; j++) {
        pb.hh[j]     = __float2bfloat16(p[2 * kstep][j]);
        pb.hh[4 + j] = __float2bfloat16(p[2 * kstep + 1][j]);
      }
      for (int dt = 0; dt < 8; dt++) {
        int d = dt * 16 + l16;
        int slot = (kstep * 4 + quad) ^ (d & 7);
        bf16x8 vb = *(const bf16x8*)(Vsm + d * 64 + slot * 8);
        o[dt] = mfma16(vb, pb.v, o[dt]);  // o^T: lane row=l16, d=quad*4+r
      }
    }
    __syncthreads();
  }
  for (int dt = 0; dt < 8; dt++) {
    union { unsigned long long u8; unsigned short us[4]; } pk;
    for (int r = 0; r < 4; r++) {
      bf16 b = __float2bfloat16(o[dt][r]);
      pk.us[r] = *(unsigned short*)&b;
    }
    *(unsigned long long*)(attnb + (size_t)g * HID + h * HD + dt * 16 + quad * 4) = pk.u8;
  }
}

extern "C" void kernel_launch(void* const* d_in, const int* in_sizes, int n_in,
                              void* d_out, int out_size, void* d_ws, size_t ws_size,
                              hipStream_t stream) {
  const float* hidden = (const float*)d_in[0];
  const int*   pos    = (const int*)d_in[1];
  const float* Wq     = (const float*)d_in[2];
  const float* Wk     = (const float*)d_in[3];
  const float* Wv     = (const float*)d_in[4];
  const float* Wo     = (const float*)d_in[5];
  const float* qw     = (const float*)d_in[6];
  const float* kw     = (const float*)d_in[7];

  float* out   = (float*)d_out;
  float* newk  = out + (size_t)S_LEN * HID;
  float* newv  = newk + (size_t)NKV * S_LEN * HD;
  float* probs = newv + (size_t)NKV * S_LEN * HD;

  char* w = (char*)d_ws;
  bf16* hb   = (bf16*)w;  w += (size_t)S_LEN * HID * 2;   // 16M; reused as qbf
  bf16* wqt  = (bf16*)w;  w += (size_t)HID * HID * 2;     // 32M; reused as wot
  bf16* wkt  = (bf16*)w;  w += (size_t)1024 * HID * 2;    // 8M;  reused as kbf
  bf16* wvt  = (bf16*)w;  w += (size_t)1024 * HID * 2;    // 8M
  float* qraw = (float*)w; w += (size_t)S_LEN * HID * 4;  // 32M; reused as attnb
  float* kraw = (float*)w; w += (size_t)S_LEN * 1024 * 4; // 8M
  bf16* vtb  = (bf16*)w;  w += (size_t)NKV * HD * S_LEN * 2;  // 4M
  bf16* qbf   = hb;
  bf16* wot   = wqt;
  bf16* kbf   = wkt;
  bf16* attnb = (bf16*)qraw;
  bf16* wqkv  = wqt;  // wqt|wkt|wvt contiguous = [6144][4096]

  cast_f32_bf16<<<(S_LEN * HID) / 1024, 256, 0, stream>>>(hidden, hb);
  transpose_cast<<<dim3(HID / 64, HID / 64), 256, 0, stream>>>(Wq, wqt, HID, HID);
  transpose_cast<<<dim3(1024 / 64, HID / 64), 256, 0, stream>>>(Wk, wkt, HID, 1024);
  transpose_cast<<<dim3(1024 / 64, HID / 64), 256, 0, stream>>>(Wv, wvt, HID, 1024);

  // combined QKV projection: N = 4096 + 1024 + 1024 = 6144 (768 blocks)
  gemm_bt<2><<<dim3(6144 / 128, S_LEN / 128), 256, 0, stream>>>(
      hb, wqkv, qraw, kraw, newv, vtb, S_LEN, 6144, HID);

  norm_rope<<<(S_LEN * NKV) / 4, 256, 0, stream>>>(kraw, kw, pos, kbf, newk, NKV);
  norm_rope<<<(S_LEN * NH) / 4, 256, 0, stream>>>(qraw, qw, pos, qbf, nullptr, NH);
  transpose_cast<<<dim3(HID / 64, HID / 64), 256, 0, stream>>>(Wo, wot, HID, HID);

  attn_kernel<<<dim3(32, 32), 256, 0, stream>>>(qbf, kbf, vtb, probs, attnb);
  gemm_bt<0><<<dim3(HID / 128, S_LEN / 128), 256, 0, stream>>>(
      attnb, wot, out, nullptr, nullptr, nullptr, S_LEN, HID, HID);
}